// Round 17
// baseline (362.722 us; speedup 1.0000x reference)
//
#include <hip/hip_runtime.h>

typedef unsigned short u16;
typedef __attribute__((ext_vector_type(8))) short short8;
typedef __attribute__((ext_vector_type(4))) float f32x4;

#define MFMA16(a,b,c) __builtin_amdgcn_mfma_f32_16x16x32_bf16(a,b,c,0,0,0)

// ---- problem constants ----
#define B_SZ   32768
#define NNODE  64
#define NB_PAIR (B_SZ*NNODE)           // 2097152
#define OUT_PROJ   327680
#define OUT_ENT    458752
#define OUT_ORTHO  458753

// ---- workspace byte offsets ----
#define OFF_SCAL   ((size_t)0)                          // float[128]; [127] = isfp32
#define OFF_ADJ    ((size_t)512)                        // u16[4096] adjb
#define OFF_BEFF   (OFF_ADJ  + 8192u)                   // float[1024]
#define OFF_WEFF   (OFF_BEFF + 4096u)                   // u16[1024*64]
#define OFF_WCAT   (OFF_WEFF + 131072u)                 // u16[32*1024]
#define OFF_S1     (OFF_WCAT + 65536u)                  // float[1024*3]
#define OFF_S2     (OFF_S1   + 12288u)                  // float[1024*3]
#define OFF_S3     (OFF_S2   + 12288u)                  // float[2048*192]
#define OFF_S4     (OFF_S3   + 2048u*192u*4u)           // float[512*2]
#define OFF_H      (OFF_S4   + 8192u)                   // float[32768*8]
#define OFF_W01    (OFF_H    + (size_t)B_SZ*8u*4u)      // float[NB_PAIR*2] (gate,w0)
#define OFF_CAN    (OFF_W01  + (size_t)NB_PAIR*2u*4u)   // canonical bf16 inputs

#define CAN_X      0u
#define CAN_WEMB   2097152u
#define CAN_WREAD  (CAN_WEMB + 65536u)
#define CAN_SCW1   (CAN_WREAD + 10240u)
#define CAN_SMALL  (CAN_SCW1 + 8192u)
#define CAN_TOTAL  (CAN_SMALL + 11008u)
#define OFF_BEX    (((OFF_CAN + (size_t)CAN_TOTAL*2u) + 63u) & ~(size_t)63u)
#define OFF_WET    (OFF_BEX + 48u*16u*2u)               // u16[1024*64] wembT
#define OFF_VW     (OFF_WET + 131072u)                  // u16[1024*64] Vw
#define OFF_VB     (OFF_VW  + 131072u)                  // float[1024] vbias
#define OFF_WC     (OFF_VB  + 4096u)                    // u16[1024*64] Wc
#define OFF_SW     (OFF_WC  + 131072u)                  // u16[192*64] Sw
#define OFF_BC2    (OFF_SW  + 24576u)                   // float[1024] bc
#define OFF_SB     (OFF_BC2 + 4096u)                    // float[192] sb
#define OFF_DR     (OFF_SB  + 1024u)                    // double[192] dred
#define WS_NEEDED  (OFF_DR  + 192u*8u)

__device__ __forceinline__ float bf2f(u16 u){
    unsigned v = ((unsigned)u) << 16;
    return __builtin_bit_cast(float, v);
}
__device__ __forceinline__ u16 f2bf(float f){
    unsigned u = __builtin_bit_cast(unsigned, f);
    u += 0x7FFFu + ((u >> 16) & 1u);           // RTN-even
    return (u16)(u >> 16);
}
__device__ __forceinline__ float sigm(float x){ return 1.f/(1.f + expf(-x)); }
__device__ __forceinline__ u16 conv_one(const void* src, int i, int isfp32){
    return isfp32 ? f2bf(((const float*)src)[i]) : ((const u16*)src)[i];
}
__device__ __forceinline__ void store_out(void* dout, int idx, float v, int isfp32){
    if (isfp32) ((float*)dout)[idx] = v;
    else        ((u16*)dout)[idx]   = f2bf(v);
}
__device__ __forceinline__ double blk_red(double v, double* sred, int tid){
    #pragma unroll
    for (int off = 32; off > 0; off >>= 1) v += __shfl_xor(v, off);
    if ((tid & 63) == 0) sred[tid >> 6] = v;
    __syncthreads();
    double r = sred[0] + sred[1] + sred[2] + sred[3];
    __syncthreads();
    return r;
}

__device__ void run_regulator(const u16* w1, const u16* b1, const u16* g,
                              const u16* be, const u16* w2, const u16* b2,
                              const float* sig, int in_dim, float* out)
{
    float h[16];
    float mu = 0.f;
    for (int i = 0; i < 16; ++i){
        float a = bf2f(b1[i]);
        for (int j = 0; j < in_dim; ++j) a += sig[j]*bf2f(w1[i*in_dim + j]);
        h[i] = a; mu += a;
    }
    mu *= 0.0625f;
    float var = 0.f;
    for (int i = 0; i < 16; ++i){ float d = h[i]-mu; var += d*d; }
    var *= 0.0625f;
    float inv = 1.f / sqrtf(var + 1e-5f);
    for (int i = 0; i < 16; ++i){
        float hn = (h[i]-mu)*inv;
        h[i] = tanhf(hn*bf2f(g[i]) + bf2f(be[i]));
    }
    for (int c = 0; c < 3; ++c){
        float o = bf2f(b2[c]);
        for (int i = 0; i < 16; ++i) o += h[i]*bf2f(w2[c*16 + i]);
        out[c] = sigm(o);
    }
}

// KP: dtype probe
__global__ __launch_bounds__(256) void kp_probe(const u16* xraw, float* scal)
{
    __shared__ int red[4];
    int tid = threadIdx.x, wave = tid>>6, lane = tid&63;
    int c = 0;
    #pragma unroll
    for (int j = 0; j < 4; ++j){
        u16 u = xraw[(tid*4 + j)*2];
        int e = (u >> 7) & 0xFF;
        if (u == 0 || (e >= 90 && e <= 140)) c++;
    }
    #pragma unroll
    for (int off = 32; off > 0; off >>= 1) c += __shfl_xor(c, off);
    if (lane == 0) red[wave] = c;
    __syncthreads();
    if (tid == 0){
        int tot = red[0]+red[1]+red[2]+red[3];
        scal[127] = (tot < 614) ? 1.0f : 0.0f;
    }
}

// KCB: canonicalize big inputs
__global__ __launch_bounds__(256) void kc_big(const void* x, const void* wemb,
    const void* wread, const void* scw1, u16* can, const float* scal)
{
    int isfp32 = scal[127] != 0.f;
    int gid = blockIdx.x*256 + threadIdx.x, stride = gridDim.x*256;
    for (int i = gid; i < 2097152; i += stride) can[CAN_X + i]     = conv_one(x, i, isfp32);
    for (int i = gid; i < 65536;   i += stride) can[CAN_WEMB + i]  = conv_one(wemb, i, isfp32);
    for (int i = gid; i < 10240;   i += stride) can[CAN_WREAD + i] = conv_one(wread, i, isfp32);
    for (int i = gid; i < 8192;    i += stride) can[CAN_SCW1 + i]  = conv_one(scw1, i, isfp32);
}

// KCS: canonicalize small inputs
struct SmallTab { const void* src[36]; int cnt[36]; int off[36]; };
__global__ __launch_bounds__(256) void kc_small(SmallTab t, u16* can, const float* scal)
{
    int isfp32 = scal[127] != 0.f;
    int gid = blockIdx.x*256 + threadIdx.x, stride = gridDim.x*256;
    for (int e = 0; e < 36; ++e){
        const void* s = t.src[e];
        u16* d = can + t.off[e];
        int n = t.cnt[e];
        for (int i = gid; i < n; i += stride) d[i] = conv_one(s, i, isfp32);
    }
}

// K0: Wcat + wembT transpose + bex static (gv row 32)
__global__ __launch_bounds__(256) void k0_wcat(const u16* wread, const u16* scw1,
    const u16* wemb, const u16* vslow, const u16* gatew, u16* wcat, u16* wembT, u16* bex)
{
    int b = blockIdx.x, tid = threadIdx.x;
    if (b < 128){
        int idx = b*256 + tid;
        int row = idx >> 10, k = idx & 1023;
        u16 v = 0;
        if (row < 10)      v = wread[row*1024 + k];
        else if (row < 18) v = scw1[(row-10)*1024 + k];
        wcat[idx] = v;
    } else if (b < 384){
        int idx = (b-128)*256 + tid;
        int m = idx >> 10, jj = idx & 1023;
        wembT[jj*64 + m] = wemb[m*1024 + jj];
    } else {
        if (tid < 16){
            float a = 0.f;
            for (int i = 0; i < 16; ++i) a += bf2f(gatew[i])*bf2f(vslow[i*16+tid]);
            bex[32*16+tid] = f2bf(a);
        }
    }
}

// K1 (B-in-regs): grid 1024 = 32 colgroups x 32 rowchunks.
__global__ __launch_bounds__(256) void k1_embed(const u16* x, const u16* wemb,
                                                const u16* bemb, float* s1)
{
    __shared__ float red[12];
    int tid = threadIdx.x, wave = tid>>6, lane = tid&63;
    int m = lane&15, quad = lane>>4;
    int cg = blockIdx.x & 31, rc = blockIdx.x >> 5;
    int col0 = cg*32 + m, col1 = col0 + 16;
    short8 b00 = *(const short8*)(wemb + col0*64 + quad*8);
    short8 b01 = *(const short8*)(wemb + col0*64 + quad*8 + 32);
    short8 b10 = *(const short8*)(wemb + col1*64 + quad*8);
    short8 b11 = *(const short8*)(wemb + col1*64 + quad*8 + 32);
    float bias0 = bf2f(bemb[col0]), bias1 = bf2f(bemb[col1]);
    float sx = 0.f, sxx = 0.f, sabs = 0.f;
    const u16* xbase = x + (size_t)(rc*1024 + wave*256 + m)*64 + quad*8;
    #pragma unroll 4
    for (int it = 0; it < 16; ++it){
        const u16* xr = xbase + (size_t)it*16*64;
        short8 a0 = *(const short8*)xr;
        short8 a1 = *(const short8*)(xr + 32);
        if (cg == 0){
            #pragma unroll
            for (int j = 0; j < 8; ++j){
                float f0 = bf2f((u16)a0[j]); sx += f0; sxx += f0*f0;
                float f1 = bf2f((u16)a1[j]); sx += f1; sxx += f1*f1;
            }
        }
        f32x4 zc = {0.f,0.f,0.f,0.f};
        f32x4 c0 = MFMA16(a0, b00, zc);
        c0 = MFMA16(a1, b01, c0);
        f32x4 c1 = MFMA16(a0, b10, zc);
        c1 = MFMA16(a1, b11, c1);
        #pragma unroll
        for (int r = 0; r < 4; ++r)
            sabs += fabsf(c0[r]+bias0) + fabsf(c1[r]+bias1);
    }
    #pragma unroll
    for (int off = 32; off > 0; off >>= 1){
        sx   += __shfl_xor(sx, off);
        sxx  += __shfl_xor(sxx, off);
        sabs += __shfl_xor(sabs, off);
    }
    if (lane == 0){ red[wave*3] = sx; red[wave*3+1] = sxx; red[wave*3+2] = sabs; }
    __syncthreads();
    if (tid == 0){
        for (int k = 0; k < 3; ++k)
            s1[blockIdx.x*3 + k] = red[k] + red[3+k] + red[6+k] + red[9+k];
    }
}

// K2: pr regulator -> pl0; build adjb + beff
__global__ __launch_bounds__(256) void k2_adj(const u16* adjw, const u16* adjm, const u16* bemb,
    const u16* w1, const u16* b1, const u16* g, const u16* be, const u16* w2, const u16* b2,
    const float* s1, float* scal, u16* adjb, float* beff)
{
    __shared__ double sred[4];
    __shared__ float raw[4096];
    __shared__ float rowsum[64];
    __shared__ float bembs[1024];
    __shared__ float pl0s;
    int tid = threadIdx.x;
    for (int i = tid; i < 1024; i += 256) bembs[i] = bf2f(bemb[i]);
    double s=0, ss=0, sa=0;
    for (int i = tid; i < 1024; i += 256){
        s += (double)s1[i*3]; ss += (double)s1[i*3+1]; sa += (double)s1[i*3+2];
    }
    double nq = 0;
    for (int i = tid; i < 4096; i += 256){ float f = bf2f(adjw[i]); nq += (double)(f*f); }
    double S  = blk_red(s,  sred, tid);
    double SS = blk_red(ss, sred, tid);
    double SA = blk_red(sa, sred, tid);
    double NQ = blk_red(nq, sred, tid);
    if (tid == 0){
        double nx = 2097152.0;
        float sg[3];
        sg[0] = (float)((SS - S*S/nx)/(nx - 1.0));
        sg[1] = (float)(SA / 33554432.0);
        sg[2] = sqrtf((float)NQ);
        float o[3];
        run_regulator(w1,b1,g,be,w2,b2, sg, 3, o);
        scal[0] = o[0]; pl0s = o[0];
    }
    __syncthreads();
    float pl0 = pl0s;
    for (int i = tid; i < 4096; i += 256)
        raw[i] = sigm(bf2f(adjw[i])*pl0) * bf2f(adjm[i]);
    __syncthreads();
    if (tid < 64){
        float r = 0.f;
        for (int mc = 0; mc < 64; ++mc) r += raw[tid*64 + mc];
        rowsum[tid] = fmaxf(r, 1e-6f);
    }
    __syncthreads();
    for (int i = tid; i < 4096; i += 256) adjb[i] = f2bf(raw[i] / rowsum[i>>6]);
    for (int o = tid; o < 1024; o += 256){
        int n = o >> 4, d = o & 15;
        float a = 0.f;
        for (int m = 0; m < 64; ++m) a += raw[n*64+m]*bembs[m*16+d];
        beff[o] = a / rowsum[n];
    }
}

// K2b (MFMA): Weff = adjb @ Wr
__global__ __launch_bounds__(256) void k2b_mfma(const u16* adjb, const u16* wembT, u16* weff)
{
    int tid = threadIdx.x, wave = tid>>6, lane = tid&63;
    int m = lane&15, quad = lane>>4;
    const u16* ar = adjb + (wave*16 + m)*64 + quad*8;
    short8 a0 = *(const short8*)ar;
    short8 a1 = *(const short8*)(ar + 32);
    int col = blockIdx.x*16 + m;
    const u16* br = wembT + col*64 + quad*8;
    short8 b0 = *(const short8*)br;
    short8 b1 = *(const short8*)(br + 32);
    f32x4 acc = {0.f,0.f,0.f,0.f};
    acc = MFMA16(a0, b0, acc);
    acc = MFMA16(a1, b1, acc);
    #pragma unroll
    for (int r = 0; r < 4; ++r)
        weff[(size_t)(wave*16 + quad*4 + r)*1024 + blockIdx.x*16 + m] = f2bf(acc[r]);
}

// KVW: Vw = V@Weff (per node), vbias = V@beff
__global__ __launch_bounds__(256) void kvw(const u16* vslow, const u16* weff, const float* beff,
                                           u16* vw, float* vbias)
{
    __shared__ float Vs[256];
    int tid = threadIdx.x, b = blockIdx.x;
    Vs[tid] = bf2f(vslow[tid]);
    __syncthreads();
    if (b < 256){
        int idx = b*256 + tid;
        int j = idx >> 6, kf = idx & 63;
        int n = j >> 4, i = j & 15;
        float a = 0.f;
        #pragma unroll
        for (int d = 0; d < 16; ++d) a += Vs[i*16+d]*bf2f(weff[(size_t)(n*16+d)*64 + kf]);
        vw[(size_t)j*64 + kf] = f2bf(a);
    } else {
        int o = (b-256)*256 + tid;
        int n = o >> 4, i = o & 15;
        float a = 0.f;
        #pragma unroll
        for (int d = 0; d < 16; ++d) a += Vs[i*16+d]*beff[n*16+d];
        vbias[o] = a;
    }
}

// K3_stats (B-in-regs): grid 1024 = 32 colgroups x 32 rowchunks. No stores.
__global__ __launch_bounds__(256) void k3_stats(const u16* x, const u16* weff, const float* beff,
                                                const u16* vw, const float* vbias, float* s2)
{
    __shared__ float red[12];
    int tid = threadIdx.x, wave = tid>>6, lane = tid&63;
    int m = lane&15, quad = lane>>4;
    int cg = blockIdx.x & 31, rc = blockIdx.x >> 5;
    int col0 = cg*32 + m, col1 = col0 + 16;
    short8 b00 = *(const short8*)(weff + (size_t)col0*64 + quad*8);
    short8 b01 = *(const short8*)(weff + (size_t)col0*64 + quad*8 + 32);
    short8 b10 = *(const short8*)(weff + (size_t)col1*64 + quad*8);
    short8 b11 = *(const short8*)(weff + (size_t)col1*64 + quad*8 + 32);
    short8 v00 = *(const short8*)(vw + (size_t)col0*64 + quad*8);
    short8 v01 = *(const short8*)(vw + (size_t)col0*64 + quad*8 + 32);
    short8 v10 = *(const short8*)(vw + (size_t)col1*64 + quad*8);
    short8 v11 = *(const short8*)(vw + (size_t)col1*64 + quad*8 + 32);
    float be0 = beff[col0], be1 = beff[col1];
    float vb0 = vbias[col0], vb1 = vbias[col1];
    float psum=0.f, pssq=0.f, pabsv=0.f;
    const u16* xbase = x + (size_t)(rc*1024 + wave*256 + m)*64 + quad*8;
    #pragma unroll 4
    for (int it = 0; it < 16; ++it){
        const u16* xr = xbase + (size_t)it*16*64;
        short8 a0 = *(const short8*)xr;
        short8 a1 = *(const short8*)(xr + 32);
        f32x4 zc = {0.f,0.f,0.f,0.f};
        f32x4 c0 = MFMA16(a0, b00, zc);
        c0 = MFMA16(a1, b01, c0);
        f32x4 c1 = MFMA16(a0, b10, zc);
        c1 = MFMA16(a1, b11, c1);
        f32x4 w0 = MFMA16(a0, v00, zc);
        w0 = MFMA16(a1, v01, w0);
        f32x4 w1 = MFMA16(a0, v10, zc);
        w1 = MFMA16(a1, v11, w1);
        #pragma unroll
        for (int r = 0; r < 4; ++r){
            float f0 = c0[r] + be0, f1 = c1[r] + be1;
            psum += f0 + f1; pssq += f0*f0 + f1*f1;
            pabsv += fabsf(w0[r] + vb0) + fabsf(w1[r] + vb1);
        }
    }
    #pragma unroll
    for (int off = 32; off > 0; off >>= 1){
        psum  += __shfl_xor(psum, off);
        pssq  += __shfl_xor(pssq, off);
        pabsv += __shfl_xor(pabsv, off);
    }
    if (lane == 0){ red[wave*3] = psum; red[wave*3+1] = pssq; red[wave*3+2] = pabsv; }
    __syncthreads();
    if (tid == 0){
        for (int k = 0; k < 3; ++k)
            s2[blockIdx.x*3 + k] = red[k] + red[3+k] + red[6+k] + red[9+k];
    }
}

// K3b: ctrl regulator + build bex dynamic rows (16-31 Bc, 33-34 e0/e1)
__global__ __launch_bounds__(256) void k3b_ctrl(const u16* wslow,
    const u16* vslow, const u16* wfast, const u16* wq, const u16* basis,
    const u16* w1, const u16* b1, const u16* g, const u16* be, const u16* w2, const u16* b2,
    const float* s2, float* scal, u16* bex)
{
    __shared__ double sred[4];
    __shared__ float ctrl2s;
    int tid = threadIdx.x;
    double s=0, ss=0, sv=0;
    for (int i = tid; i < 1024; i += 256){
        s += (double)s2[i*3]; ss += (double)s2[i*3+1]; sv += (double)s2[i*3+2];
    }
    float wf = bf2f(wslow[tid]);
    double nq = (double)(wf*wf);
    double S  = blk_red(s,  sred, tid);
    double SS = blk_red(ss, sred, tid);
    double SV = blk_red(sv, sred, tid);
    double NQ = blk_red(nq, sred, tid);
    if (tid == 0){
        double M = 33554432.0;
        float sg[3];
        sg[0] = (float)((SS - S*S/M)/(M - 1.0));
        sg[1] = (float)(SV / M);
        sg[2] = sqrtf((float)NQ);
        float o[3];
        run_regulator(w1,b1,g,be,w2,b2, sg, 3, o);
        scal[1] = o[0]; scal[2] = o[2];
        ctrl2s = o[2];
    }
    __syncthreads();
    float ctrl2 = ctrl2s;
    if (tid < 64){
        #pragma unroll
        for (int j = 0; j < 4; ++j){
            int idx = tid*4 + j;
            int d = idx >> 4, k = idx & 15;
            bex[(16+d)*16+k] = f2bf(bf2f(vslow[idx]) + ctrl2*bf2f(wfast[idx]));
        }
    } else if (tid < 96){
        int a = (tid-64) >> 4, k = (tid-64) & 15;
        float e = 0.f;
        for (int d = 0; d < 16; ++d){
            float bq = 0.f;
            for (int j = 0; j < 16; ++j) bq += bf2f(basis[a*16+j])*bf2f(wq[j*16+d]);
            e += bq*(bf2f(vslow[d*16+k]) + ctrl2*bf2f(wfast[d*16+k]));
        }
        bex[(33+a)*16+k] = f2bf(0.25f*e);
    }
}

// KBW: build Wc[(n,d)][64], Sw[(n,j)][64], bc[1024], sb[192]
__global__ __launch_bounds__(256) void kbw(const u16* bex, const u16* weff, const float* beff,
                                           const u16* gateb, u16* wc, u16* sw,
                                           float* bc, float* sb)
{
    __shared__ float BcL[256], gvL[16], e0L[16], e1L[16];
    int tid = threadIdx.x;
    if (tid < 256) BcL[tid] = bf2f(bex[(16 + (tid>>4))*16 + (tid&15)]);
    if (tid < 16){
        gvL[tid] = bf2f(bex[32*16+tid]);
        e0L[tid] = bf2f(bex[33*16+tid]);
        e1L[tid] = bf2f(bex[34*16+tid]);
    }
    __syncthreads();
    int id = blockIdx.x*256 + tid;
    if (id < 65536){
        int col = id >> 6, k = id & 63;
        int n = col >> 4, d = col & 15;
        float a = 0.f;
        #pragma unroll
        for (int dd = 0; dd < 16; ++dd)
            a += BcL[d*16+dd]*bf2f(weff[(size_t)(n*16+dd)*64 + k]);
        wc[(size_t)col*64 + k] = f2bf(a);
    } else if (id < 77824){
        int j2 = id - 65536;
        int scol = j2 >> 6, k = j2 & 63;
        int n = scol/3, j = scol - n*3;
        const float* sr = (j==0) ? gvL : (j==1) ? e0L : e1L;
        float a = 0.f;
        #pragma unroll
        for (int dd = 0; dd < 16; ++dd)
            a += sr[dd]*bf2f(weff[(size_t)(n*16+dd)*64 + k]);
        sw[(size_t)scol*64 + k] = f2bf(a);
    } else if (id < 78848){
        int col = id - 77824;
        int n = col >> 4, d = col & 15;
        float a = 0.f;
        #pragma unroll
        for (int dd = 0; dd < 16; ++dd) a += BcL[d*16+dd]*beff[n*16+dd];
        bc[col] = a;
    } else if (id < 79040){
        int s = id - 78848;
        int n = s/3, j = s - n*3;
        const float* sr = (j==0) ? gvL : (j==1) ? e0L : e1L;
        float a = 0.f;
        #pragma unroll
        for (int dd = 0; dd < 16; ++dd) a += sr[dd]*beff[n*16+dd];
        if (j == 0) a += bf2f(gateb[0]);
        sb[s] = a;
    }
}

// K4_stats: gates/softmax/entropy + per-node stats from x. 2048 blocks x 16 rows.
#define SCP 193
__global__ __launch_bounds__(256) void k4_stats(const u16* x, const u16* wc, const u16* sw,
    const float* bc, const float* sb, const float* scal, float* wbuf, float* s3)
{
    __shared__ float sc[16*SCP];
    __shared__ float gt[1024];
    __shared__ float entp[256];
    __shared__ float snode[128];
    int tid = threadIdx.x, wave = tid>>6, lane = tid&63;
    int m = lane&15, quad = lane>>4;
    int row0 = blockIdx.x*16;
    const u16* xr = x + (row0 + m)*64 + quad*8;
    short8 a0 = *(const short8*)xr;
    short8 a1 = *(const short8*)(xr + 32);
    float ctrl0 = scal[1];
    #pragma unroll
    for (int tt = 0; tt < 3; ++tt){
        int ct = wave*3 + tt;
        int scol = ct*16 + m;
        const u16* br = sw + (size_t)scol*64 + quad*8;
        short8 b0 = *(const short8*)br;
        short8 b1 = *(const short8*)(br + 32);
        f32x4 zc = {0.f,0.f,0.f,0.f};
        f32x4 c = MFMA16(a0, b0, zc);
        c = MFMA16(a1, b1, c);
        float sbv = sb[scol];
        #pragma unroll
        for (int r = 0; r < 4; ++r)
            sc[(quad*4+r)*SCP + scol] = c[r] + sbv;
    }
    __syncthreads();
    {
        int n = tid & 63, rgrp = tid >> 6;
        float ent = 0.f;
        #pragma unroll
        for (int rr = 0; rr < 4; ++rr){
            int row = rgrp*4 + rr;
            float gd  = sc[row*SCP + 3*n];
            float e0d = sc[row*SCP + 3*n + 1];
            float e1d = sc[row*SCP + 3*n + 2];
            float gate = ctrl0 / (1.f + __expf(-gd));
            float l0 = gate*e0d, l1 = gate*e1d;
            float w1v = 1.f/(1.f + __expf(l0 - l1));
            float w0v = 1.f - w1v;
            ent += -(w0v*__logf(w0v + 1e-8f) + w1v*__logf(w1v + 1e-8f));
            gt[row*64 + n] = gate;
            float2 wv; wv.x = gate; wv.y = w0v;
            *(float2*)(wbuf + (size_t)(row0 + row)*128 + n*2) = wv;
        }
        entp[tid] = ent;
    }
    __syncthreads();
    #pragma unroll
    for (int tt = 0; tt < 16; ++tt){
        int n = wave*16 + tt;
        int col = n*16 + m;
        const u16* br = wc + (size_t)col*64 + quad*8;
        short8 b0 = *(const short8*)br;
        short8 b1 = *(const short8*)(br + 32);
        f32x4 zc = {0.f,0.f,0.f,0.f};
        f32x4 c = MFMA16(a0, b0, zc);
        c = MFMA16(a1, b1, c);
        float bcv = bc[col];
        float ps = 0.f, pq = 0.f;
        #pragma unroll
        for (int r = 0; r < 4; ++r){
            float gate = gt[(quad*4+r)*64 + n];
            float xp = gate*(c[r] + bcv);
            ps += xp; pq += xp*xp;
        }
        #pragma unroll
        for (int off = 32; off > 0; off >>= 1){
            ps += __shfl_xor(ps, off);
            pq += __shfl_xor(pq, off);
        }
        if (lane == 0){ snode[n] = ps; snode[64+n] = pq; }
    }
    __syncthreads();
    if (tid < 192){
        float v;
        if (tid < 128) v = snode[tid];
        else { int n = tid-128; v = entp[n]+entp[64+n]+entp[128+n]+entp[192+n]; }
        s3[(size_t)blockIdx.x*192 + tid] = v;
    }
}

// K5a: parallel column reduction of s3[2048][192] -> dred[192]
__global__ __launch_bounds__(256) void k5a_red(const float* s3, double* dred)
{
    __shared__ double sred[4];
    int tid = threadIdx.x, col = blockIdx.x;
    double a = 0;
    for (int i = tid; i < 2048; i += 256) a += (double)s3[(size_t)i*192 + col];
    #pragma unroll
    for (int off = 32; off > 0; off >>= 1) a += __shfl_xor(a, off);
    if ((tid & 63) == 0) sred[tid >> 6] = a;
    __syncthreads();
    if (tid == 0) dred[col] = sred[0]+sred[1]+sred[2]+sred[3];
}

// K5b: per-node regulator -> infl[64]; entropy(node63), ortho. 1 block, 64 threads.
__global__ __launch_bounds__(64) void k5b_infl(const u16* basis,
    const u16* w1, const u16* b1, const u16* g, const u16* be, const u16* w2, const u16* b2,
    const double* dred, float* scal, void* dout)
{
    int n = threadIdx.x;
    int isfp32 = scal[127] != 0.f;
    double sum = dred[n], ssq = dred[64+n], ent = dred[128+n];
    double Mn = 524288.0;
    float varn = (float)((ssq - sum*sum/Mn)/(Mn - 1.0));
    float entm = (float)(ent / 32768.0);
    float b0[16], b1v[16];
    for (int d = 0; d < 16; ++d){ b0[d] = bf2f(basis[d]); b1v[d] = bf2f(basis[16+d]); }
    float g00=0.f, g01=0.f, g11=0.f;
    for (int d = 0; d < 16; ++d){ g00 += b0[d]*b0[d]; g01 += b0[d]*b1v[d]; g11 += b1v[d]*b1v[d]; }
    float ortho = sqrtf((g00-1.f)*(g00-1.f) + 2.f*g01*g01 + (g11-1.f)*(g11-1.f));
    float sg[3] = {varn, entm, ortho};
    float o[3];
    run_regulator(w1,b1,g,be,w2,b2, sg, 3, o);
    scal[4+n] = o[0];
    if (n == 63){ scal[68] = entm;  store_out(dout, OUT_ENT,   entm,  isfp32); }
    if (n == 0) { scal[69] = ortho; store_out(dout, OUT_ORTHO, ortho, isfp32); }
}

// K6: full-K readout, 512-thread blocks, intra-block split-K.
// Wave w: row-set (w&3), k-half (w>>2). Partials combined via padded LDS.
#define XSP 132
__global__ __launch_bounds__(512) void k6_read(const u16* x, const float* wbuf,
    const u16* wc, const float* bc, const u16* wcat,
    const u16* basis, const u16* bread, const float* scal,
    void* dout, float* hbuf, float* s4)
{
    __shared__ unsigned gwP[64*65];              // [64 rows][65] lo=gate, hi=w0 (bf16), padded
    __shared__ u16 xs[8*16*XSP];                 // per-wave staging
    __shared__ float pacc[4*64*9];               // partial acc exchange, stride 9 (conflict-free)
    __shared__ float infl_s[64], b0s[16], b1s[16], brd[16];
    __shared__ float red[16];
    int tid = threadIdx.x;
    int isfp32 = scal[127] != 0.f;
    for (int i = tid; i < 4096; i += 512){
        float2 gw = *(const float2*)(wbuf + (size_t)blockIdx.x*8192 + i*2);
        gwP[(i >> 6)*65 + (i & 63)] = ((unsigned)f2bf(gw.y) << 16) | (unsigned)f2bf(gw.x);
    }
    if (tid < 64) infl_s[tid] = scal[4+tid];
    if (tid < 16){
        b0s[tid] = bf2f(basis[tid]);
        b1s[tid] = bf2f(basis[16+tid]);
        brd[tid] = (tid < 10) ? bf2f(bread[tid]) : 0.f;
    }
    __syncthreads();
    int wave = tid>>6, lane = tid&63;
    int wset = wave & 3, half = wave >> 2;
    int m = lane&15, quad = lane>>4;
    int row = blockIdx.x*64 + wset*16 + m;
    const u16* xr = x + (size_t)row*64 + quad*8;
    short8 a0 = *(const short8*)xr;
    short8 a1 = *(const short8*)(xr + 32);
    u16* xsw = xs + wave*16*XSP;
    f32x4 acc0 = {0.f,0.f,0.f,0.f}, acc1 = {0.f,0.f,0.f,0.f};
    float psum = 0.f, pssq = 0.f;
    for (int c8 = half*4; c8 < half*4 + 4; ++c8){
        #pragma unroll
        for (int t = 0; t < 8; ++t){
            int n = c8*8 + t;
            int col = n*16 + m;
            const u16* br = wc + (size_t)col*64 + quad*8;
            short8 b0 = *(const short8*)br;
            short8 b1 = *(const short8*)(br + 32);
            f32x4 zc = {0.f,0.f,0.f,0.f};
            f32x4 c = MFMA16(a0, b0, zc);
            c = MFMA16(a1, b1, c);
            float bcv = bc[col];
            float fi = infl_s[n], om = 1.f - fi;
            #pragma unroll
            for (int r = 0; r < 4; ++r){
                unsigned gv = gwP[(wset*16 + quad*4 + r)*65 + n];
                float gate = bf2f((u16)(gv & 0xFFFFu));
                float w0v  = bf2f((u16)(gv >> 16));
                float xp = gate*(c[r] + bcv);
                float xf = om*xp + fi*(w0v*b0s[m] + (1.f-w0v)*b1s[m]);
                psum += xf; pssq += xf*xf;
                xsw[(quad*4+r)*XSP + t*16 + m] = f2bf(xf);
            }
        }
        #pragma unroll
        for (int kk = 0; kk < 4; ++kk){
            short8 af = *(const short8*)(xsw + m*XSP + kk*32 + quad*8);
            short8 bb0 = *(const short8*)(wcat + m*1024      + c8*128 + kk*32 + quad*8);
            short8 bb1 = *(const short8*)(wcat + (16+m)*1024 + c8*128 + kk*32 + quad*8);
            acc0 = MFMA16(af, bb0, acc0);
            acc1 = MFMA16(af, bb1, acc1);
        }
    }
    if (half == 1){
        float* pp = pacc + (wset*64 + lane)*9;
        pp[0]=acc0[0]; pp[1]=acc0[1]; pp[2]=acc0[2]; pp[3]=acc0[3];
        pp[4]=acc1[0]; pp[5]=acc1[1]; pp[6]=acc1[2]; pp[7]=acc1[3];
    }
    #pragma unroll
    for (int off = 32; off > 0; off >>= 1){
        psum += __shfl_xor(psum, off);
        pssq += __shfl_xor(pssq, off);
    }
    if (lane == 0){ red[wave] = psum; red[8+wave] = pssq; }
    __syncthreads();
    if (half == 0){
        const float* pp = pacc + (wset*64 + lane)*9;
        acc0[0]+=pp[0]; acc0[1]+=pp[1]; acc0[2]+=pp[2]; acc0[3]+=pp[3];
        acc1[0]+=pp[4]; acc1[1]+=pp[5]; acc1[2]+=pp[6]; acc1[3]+=pp[7];
        int rowbase = blockIdx.x*64 + wset*16 + quad*4;
        #pragma unroll
        for (int r = 0; r < 4; ++r){
            int rowg = rowbase + r;
            if (m < 10) store_out(dout, rowg*10 + m, acc0[r] + brd[m], isfp32);
            else        hbuf[rowg*8 + (m-10)] = fmaxf(acc0[r], 0.f);
            if (m < 2)  hbuf[rowg*8 + 6 + m]  = fmaxf(acc1[r], 0.f);
        }
    }
    if (tid == 0){
        float sa = 0.f, sb2 = 0.f;
        #pragma unroll
        for (int w = 0; w < 8; ++w){ sa += red[w]; sb2 += red[8+w]; }
        s4[blockIdx.x*2]   = sa;
        s4[blockIdx.x*2+1] = sb2;
    }
}

// K7: gain regulator (s4 512 rows x 2)
__global__ __launch_bounds__(256) void k7_gain(
    const u16* w1, const u16* b1, const u16* g, const u16* be, const u16* w2, const u16* b2,
    const float* s4, float* scal)
{
    __shared__ double sred[4];
    int tid = threadIdx.x;
    double s=0, ss=0;
    for (int i = tid; i < 512; i += 256){ s += (double)s4[i*2]; ss += (double)s4[i*2+1]; }
    double S  = blk_red(s,  sred, tid);
    double SS = blk_red(ss, sred, tid);
    if (tid == 0){
        double M = 33554432.0;
        float sg[2];
        sg[0] = (float)((SS - S*S/M)/(M - 1.0));
        sg[1] = scal[68];
        float o[3];
        run_regulator(w1,b1,g,be,w2,b2, sg, 2, o);
        scal[3] = o[0];
    }
}

// K8: proj = (h @ sc_w2^T) * gain
__global__ __launch_bounds__(256) void k8_proj(const float* hbuf, const u16* scw2,
                                               const float* scal, void* dout)
{
    __shared__ float w2s[32];
    int tid = threadIdx.x;
    int isfp32 = scal[127] != 0.f;
    if (tid < 32) w2s[tid] = bf2f(scw2[tid]);
    __syncthreads();
    int b = blockIdx.x*256 + tid;
    float gain = scal[3];
    const float* h = hbuf + (size_t)b*8;
    float hv[8];
    #pragma unroll
    for (int k = 0; k < 8; ++k) hv[k] = h[k];
    #pragma unroll
    for (int i = 0; i < 4; ++i){
        float o = 0.f;
        #pragma unroll
        for (int k = 0; k < 8; ++k) o += hv[k]*w2s[i*8+k];
        store_out(dout, OUT_PROJ + b*4 + i, o*gain, isfp32);
    }
}

extern "C" void kernel_launch(void* const* d_in, const int* in_sizes, int n_in,
                              void* d_out, int out_size, void* d_ws, size_t ws_size,
                              hipStream_t stream)
{
    if (ws_size < WS_NEEDED) return;

    char* ws = (char*)d_ws;
    float* scal  = (float*)(ws + OFF_SCAL);
    u16*   adjb  = (u16*)  (ws + OFF_ADJ);
    float* beff  = (float*)(ws + OFF_BEFF);
    u16*   weff  = (u16*)  (ws + OFF_WEFF);
    u16*   wcat  = (u16*)  (ws + OFF_WCAT);
    float* s1    = (float*)(ws + OFF_S1);
    float* s2    = (float*)(ws + OFF_S2);
    float* s3    = (float*)(ws + OFF_S3);
    float* s4    = (float*)(ws + OFF_S4);
    float* hbuf  = (float*)(ws + OFF_H);
    float* wbuf  = (float*)(ws + OFF_W01);
    u16*   can   = (u16*)  (ws + OFF_CAN);
    u16*   bex   = (u16*)  (ws + OFF_BEX);
    u16*   wembT = (u16*)  (ws + OFF_WET);
    u16*   vw    = (u16*)  (ws + OFF_VW);
    float* vbias = (float*)(ws + OFF_VB);
    u16*   wc    = (u16*)  (ws + OFF_WC);
    u16*   sw    = (u16*)  (ws + OFF_SW);
    float* bc    = (float*)(ws + OFF_BC2);
    float* sb    = (float*)(ws + OFF_SB);
    double* dred = (double*)(ws + OFF_DR);

    static const int sidx[36] = {2,3,4,5,6,7,8,9,10,11,13,15,
        16,17,18,19,20,21, 22,23,24,25,26,27, 28,29,30,31,32,33, 34,35,36,37,38,39};
    static const int scnt[36] = {1024,4096,4096,256,256,16,1,256,32,256,32,10,
        48,16,16,16,48,3, 48,16,16,16,48,3, 48,16,16,16,48,3, 32,16,16,16,48,3};
    SmallTab t;
    const u16* canp[40];
    {
        int off = (int)CAN_SMALL;
        for (int j = 0; j < 36; ++j){
            t.src[j] = d_in[sidx[j]];
            t.cnt[j] = scnt[j];
            t.off[j] = off;
            canp[sidx[j]] = can + off;
            off += (scnt[j] + 7) & ~7;
        }
    }
    canp[0]  = can + CAN_X;
    canp[1]  = can + CAN_WEMB;
    canp[12] = can + CAN_SCW1;
    canp[14] = can + CAN_WREAD;

    const u16* pr_[6]; const u16* cr_[6]; const u16* sr_[6]; const u16* sc_[6];
    for (int i = 0; i < 6; ++i){
        pr_[i] = canp[16+i]; cr_[i] = canp[22+i];
        sr_[i] = canp[28+i]; sc_[i] = canp[34+i];
    }

    kp_probe<<<1,   256, 0, stream>>>((const u16*)d_in[0], scal);
    kc_big  <<<1024,256, 0, stream>>>(d_in[0], d_in[1], d_in[14], d_in[12], can, scal);
    kc_small<<<16,  256, 0, stream>>>(t, can, scal);
    k0_wcat <<<385, 256, 0, stream>>>(canp[14], canp[12], canp[1], canp[5], canp[7],
                 wcat, wembT, bex);
    k1_embed<<<1024,256, 0, stream>>>(canp[0], canp[1], canp[2], s1);
    k2_adj  <<<1,   256, 0, stream>>>(canp[3], canp[4], canp[2],
                 pr_[0],pr_[1],pr_[2],pr_[3],pr_[4],pr_[5], s1, scal, adjb, beff);
    k2b_mfma<<<64,  256, 0, stream>>>(adjb, wembT, weff);
    kvw     <<<260, 256, 0, stream>>>(canp[5], weff, beff, vw, vbias);
    k3_stats<<<1024,256, 0, stream>>>(canp[0], weff, beff, vw, vbias, s2);
    k3b_ctrl<<<1,   256, 0, stream>>>(canp[6], canp[5], canp[9], canp[11], canp[10],
                 cr_[0],cr_[1],cr_[2],cr_[3],cr_[4],cr_[5], s2, scal, bex);
    kbw     <<<312, 256, 0, stream>>>(bex, weff, beff, canp[8], wc, sw, bc, sb);
    k4_stats<<<2048,256, 0, stream>>>(canp[0], wc, sw, bc, sb, scal, wbuf, s3);
    k5a_red <<<192, 256, 0, stream>>>(s3, dred);
    k5b_infl<<<1,   64,  0, stream>>>(canp[10],
                 sr_[0],sr_[1],sr_[2],sr_[3],sr_[4],sr_[5], dred, scal, d_out);
    k6_read <<<512, 512, 0, stream>>>(canp[0], wbuf, wc, bc, wcat, canp[10], canp[15],
                 scal, d_out, hbuf, s4);
    k7_gain <<<1,   256, 0, stream>>>(
                 sc_[0],sc_[1],sc_[2],sc_[3],sc_[4],sc_[5], s4, scal);
    k8_proj <<<128, 256, 0, stream>>>(hbuf, canp[13], scal, d_out);
}

// Round 18
// 351.471 us; speedup vs baseline: 1.0320x; 1.0320x over previous
//
#include <hip/hip_runtime.h>

typedef unsigned short u16;
typedef __attribute__((ext_vector_type(8))) short short8;
typedef __attribute__((ext_vector_type(4))) float f32x4;

#define MFMA16(a,b,c) __builtin_amdgcn_mfma_f32_16x16x32_bf16(a,b,c,0,0,0)

// ---- problem constants ----
#define B_SZ   32768
#define NNODE  64
#define NB_PAIR (B_SZ*NNODE)           // 2097152
#define OUT_PROJ   327680
#define OUT_ENT    458752
#define OUT_ORTHO  458753

// ---- workspace byte offsets ----
#define OFF_SCAL   ((size_t)0)                          // float[128]; [127] = isfp32
#define OFF_ADJ    ((size_t)512)                        // u16[4096] adjb
#define OFF_BEFF   (OFF_ADJ  + 8192u)                   // float[1024]
#define OFF_WEFF   (OFF_BEFF + 4096u)                   // u16[1024*64]
#define OFF_WCAT   (OFF_WEFF + 131072u)                 // u16[32*1024]
#define OFF_S1     (OFF_WCAT + 65536u)                  // float[1024*3]
#define OFF_S2     (OFF_S1   + 12288u)                  // float[1024*3]
#define OFF_S3     (OFF_S2   + 12288u)                  // float[2048*192]
#define OFF_S4     (OFF_S3   + 2048u*192u*4u)           // float[512*2]
#define OFF_H      (OFF_S4   + 8192u)                   // float[32768*8]
#define OFF_W01    (OFF_H    + (size_t)B_SZ*8u*4u)      // float[NB_PAIR*2] (gate,w0)
#define OFF_CAN    (OFF_W01  + (size_t)NB_PAIR*2u*4u)   // canonical bf16 inputs

#define CAN_X      0u
#define CAN_WEMB   2097152u
#define CAN_WREAD  (CAN_WEMB + 65536u)
#define CAN_SCW1   (CAN_WREAD + 10240u)
#define CAN_SMALL  (CAN_SCW1 + 8192u)
#define CAN_TOTAL  (CAN_SMALL + 11008u)
#define OFF_BEX    (((OFF_CAN + (size_t)CAN_TOTAL*2u) + 63u) & ~(size_t)63u)
#define OFF_WET    (OFF_BEX + 48u*16u*2u)               // u16[1024*64] wembT
#define OFF_VW     (OFF_WET + 131072u)                  // u16[1024*64] Vw
#define OFF_VB     (OFF_VW  + 131072u)                  // float[1024] vbias
#define OFF_WC     (OFF_VB  + 4096u)                    // u16[1024*64] Wc
#define OFF_SW     (OFF_WC  + 131072u)                  // u16[192*64] Sw
#define OFF_BC2    (OFF_SW  + 24576u)                   // float[1024] bc
#define OFF_SB     (OFF_BC2 + 4096u)                    // float[192] sb
#define OFF_DR     (OFF_SB  + 1024u)                    // double[192] dred
#define WS_NEEDED  (OFF_DR  + 192u*8u)

__device__ __forceinline__ float bf2f(u16 u){
    unsigned v = ((unsigned)u) << 16;
    return __builtin_bit_cast(float, v);
}
__device__ __forceinline__ u16 f2bf(float f){
    unsigned u = __builtin_bit_cast(unsigned, f);
    u += 0x7FFFu + ((u >> 16) & 1u);           // RTN-even
    return (u16)(u >> 16);
}
__device__ __forceinline__ float sigm(float x){ return 1.f/(1.f + expf(-x)); }
__device__ __forceinline__ u16 conv_one(const void* src, int i, int isfp32){
    return isfp32 ? f2bf(((const float*)src)[i]) : ((const u16*)src)[i];
}
__device__ __forceinline__ void store_out(void* dout, int idx, float v, int isfp32){
    if (isfp32) ((float*)dout)[idx] = v;
    else        ((u16*)dout)[idx]   = f2bf(v);
}
__device__ __forceinline__ double blk_red(double v, double* sred, int tid){
    #pragma unroll
    for (int off = 32; off > 0; off >>= 1) v += __shfl_xor(v, off);
    if ((tid & 63) == 0) sred[tid >> 6] = v;
    __syncthreads();
    double r = sred[0] + sred[1] + sred[2] + sred[3];
    __syncthreads();
    return r;
}

__device__ void run_regulator(const u16* w1, const u16* b1, const u16* g,
                              const u16* be, const u16* w2, const u16* b2,
                              const float* sig, int in_dim, float* out)
{
    float h[16];
    float mu = 0.f;
    for (int i = 0; i < 16; ++i){
        float a = bf2f(b1[i]);
        for (int j = 0; j < in_dim; ++j) a += sig[j]*bf2f(w1[i*in_dim + j]);
        h[i] = a; mu += a;
    }
    mu *= 0.0625f;
    float var = 0.f;
    for (int i = 0; i < 16; ++i){ float d = h[i]-mu; var += d*d; }
    var *= 0.0625f;
    float inv = 1.f / sqrtf(var + 1e-5f);
    for (int i = 0; i < 16; ++i){
        float hn = (h[i]-mu)*inv;
        h[i] = tanhf(hn*bf2f(g[i]) + bf2f(be[i]));
    }
    for (int c = 0; c < 3; ++c){
        float o = bf2f(b2[c]);
        for (int i = 0; i < 16; ++i) o += h[i]*bf2f(w2[c*16 + i]);
        out[c] = sigm(o);
    }
}

// KP: dtype probe
__global__ __launch_bounds__(256) void kp_probe(const u16* xraw, float* scal)
{
    __shared__ int red[4];
    int tid = threadIdx.x, wave = tid>>6, lane = tid&63;
    int c = 0;
    #pragma unroll
    for (int j = 0; j < 4; ++j){
        u16 u = xraw[(tid*4 + j)*2];
        int e = (u >> 7) & 0xFF;
        if (u == 0 || (e >= 90 && e <= 140)) c++;
    }
    #pragma unroll
    for (int off = 32; off > 0; off >>= 1) c += __shfl_xor(c, off);
    if (lane == 0) red[wave] = c;
    __syncthreads();
    if (tid == 0){
        int tot = red[0]+red[1]+red[2]+red[3];
        scal[127] = (tot < 614) ? 1.0f : 0.0f;
    }
}

// KCB: canonicalize big inputs
__global__ __launch_bounds__(256) void kc_big(const void* x, const void* wemb,
    const void* wread, const void* scw1, u16* can, const float* scal)
{
    int isfp32 = scal[127] != 0.f;
    int gid = blockIdx.x*256 + threadIdx.x, stride = gridDim.x*256;
    for (int i = gid; i < 2097152; i += stride) can[CAN_X + i]     = conv_one(x, i, isfp32);
    for (int i = gid; i < 65536;   i += stride) can[CAN_WEMB + i]  = conv_one(wemb, i, isfp32);
    for (int i = gid; i < 10240;   i += stride) can[CAN_WREAD + i] = conv_one(wread, i, isfp32);
    for (int i = gid; i < 8192;    i += stride) can[CAN_SCW1 + i]  = conv_one(scw1, i, isfp32);
}

// KCS: canonicalize small inputs
struct SmallTab { const void* src[36]; int cnt[36]; int off[36]; };
__global__ __launch_bounds__(256) void kc_small(SmallTab t, u16* can, const float* scal)
{
    int isfp32 = scal[127] != 0.f;
    int gid = blockIdx.x*256 + threadIdx.x, stride = gridDim.x*256;
    for (int e = 0; e < 36; ++e){
        const void* s = t.src[e];
        u16* d = can + t.off[e];
        int n = t.cnt[e];
        for (int i = gid; i < n; i += stride) d[i] = conv_one(s, i, isfp32);
    }
}

// K0: Wcat + wembT transpose + bex static (gv row 32)
__global__ __launch_bounds__(256) void k0_wcat(const u16* wread, const u16* scw1,
    const u16* wemb, const u16* vslow, const u16* gatew, u16* wcat, u16* wembT, u16* bex)
{
    int b = blockIdx.x, tid = threadIdx.x;
    if (b < 128){
        int idx = b*256 + tid;
        int row = idx >> 10, k = idx & 1023;
        u16 v = 0;
        if (row < 10)      v = wread[row*1024 + k];
        else if (row < 18) v = scw1[(row-10)*1024 + k];
        wcat[idx] = v;
    } else if (b < 384){
        int idx = (b-128)*256 + tid;
        int m = idx >> 10, jj = idx & 1023;
        wembT[jj*64 + m] = wemb[m*1024 + jj];
    } else {
        if (tid < 16){
            float a = 0.f;
            for (int i = 0; i < 16; ++i) a += bf2f(gatew[i])*bf2f(vslow[i*16+tid]);
            bex[32*16+tid] = f2bf(a);
        }
    }
}

// K1 (B-in-regs): grid 1024 = 32 colgroups x 32 rowchunks.
__global__ __launch_bounds__(256) void k1_embed(const u16* x, const u16* wemb,
                                                const u16* bemb, float* s1)
{
    __shared__ float red[12];
    int tid = threadIdx.x, wave = tid>>6, lane = tid&63;
    int m = lane&15, quad = lane>>4;
    int cg = blockIdx.x & 31, rc = blockIdx.x >> 5;
    int col0 = cg*32 + m, col1 = col0 + 16;
    short8 b00 = *(const short8*)(wemb + col0*64 + quad*8);
    short8 b01 = *(const short8*)(wemb + col0*64 + quad*8 + 32);
    short8 b10 = *(const short8*)(wemb + col1*64 + quad*8);
    short8 b11 = *(const short8*)(wemb + col1*64 + quad*8 + 32);
    float bias0 = bf2f(bemb[col0]), bias1 = bf2f(bemb[col1]);
    float sx = 0.f, sxx = 0.f, sabs = 0.f;
    const u16* xbase = x + (size_t)(rc*1024 + wave*256 + m)*64 + quad*8;
    #pragma unroll 4
    for (int it = 0; it < 16; ++it){
        const u16* xr = xbase + (size_t)it*16*64;
        short8 a0 = *(const short8*)xr;
        short8 a1 = *(const short8*)(xr + 32);
        if (cg == 0){
            #pragma unroll
            for (int j = 0; j < 8; ++j){
                float f0 = bf2f((u16)a0[j]); sx += f0; sxx += f0*f0;
                float f1 = bf2f((u16)a1[j]); sx += f1; sxx += f1*f1;
            }
        }
        f32x4 zc = {0.f,0.f,0.f,0.f};
        f32x4 c0 = MFMA16(a0, b00, zc);
        c0 = MFMA16(a1, b01, c0);
        f32x4 c1 = MFMA16(a0, b10, zc);
        c1 = MFMA16(a1, b11, c1);
        #pragma unroll
        for (int r = 0; r < 4; ++r)
            sabs += fabsf(c0[r]+bias0) + fabsf(c1[r]+bias1);
    }
    #pragma unroll
    for (int off = 32; off > 0; off >>= 1){
        sx   += __shfl_xor(sx, off);
        sxx  += __shfl_xor(sxx, off);
        sabs += __shfl_xor(sabs, off);
    }
    if (lane == 0){ red[wave*3] = sx; red[wave*3+1] = sxx; red[wave*3+2] = sabs; }
    __syncthreads();
    if (tid == 0){
        for (int k = 0; k < 3; ++k)
            s1[blockIdx.x*3 + k] = red[k] + red[3+k] + red[6+k] + red[9+k];
    }
}

// K2: pr regulator -> pl0; build adjb + beff
__global__ __launch_bounds__(256) void k2_adj(const u16* adjw, const u16* adjm, const u16* bemb,
    const u16* w1, const u16* b1, const u16* g, const u16* be, const u16* w2, const u16* b2,
    const float* s1, float* scal, u16* adjb, float* beff)
{
    __shared__ double sred[4];
    __shared__ float raw[4096];
    __shared__ float rowsum[64];
    __shared__ float bembs[1024];
    __shared__ float pl0s;
    int tid = threadIdx.x;
    for (int i = tid; i < 1024; i += 256) bembs[i] = bf2f(bemb[i]);
    double s=0, ss=0, sa=0;
    for (int i = tid; i < 1024; i += 256){
        s += (double)s1[i*3]; ss += (double)s1[i*3+1]; sa += (double)s1[i*3+2];
    }
    double nq = 0;
    for (int i = tid; i < 4096; i += 256){ float f = bf2f(adjw[i]); nq += (double)(f*f); }
    double S  = blk_red(s,  sred, tid);
    double SS = blk_red(ss, sred, tid);
    double SA = blk_red(sa, sred, tid);
    double NQ = blk_red(nq, sred, tid);
    if (tid == 0){
        double nx = 2097152.0;
        float sg[3];
        sg[0] = (float)((SS - S*S/nx)/(nx - 1.0));
        sg[1] = (float)(SA / 33554432.0);
        sg[2] = sqrtf((float)NQ);
        float o[3];
        run_regulator(w1,b1,g,be,w2,b2, sg, 3, o);
        scal[0] = o[0]; pl0s = o[0];
    }
    __syncthreads();
    float pl0 = pl0s;
    for (int i = tid; i < 4096; i += 256)
        raw[i] = sigm(bf2f(adjw[i])*pl0) * bf2f(adjm[i]);
    __syncthreads();
    if (tid < 64){
        float r = 0.f;
        for (int mc = 0; mc < 64; ++mc) r += raw[tid*64 + mc];
        rowsum[tid] = fmaxf(r, 1e-6f);
    }
    __syncthreads();
    for (int i = tid; i < 4096; i += 256) adjb[i] = f2bf(raw[i] / rowsum[i>>6]);
    for (int o = tid; o < 1024; o += 256){
        int n = o >> 4, d = o & 15;
        float a = 0.f;
        for (int m = 0; m < 64; ++m) a += raw[n*64+m]*bembs[m*16+d];
        beff[o] = a / rowsum[n];
    }
}

// K2b (MFMA): Weff = adjb @ Wr
__global__ __launch_bounds__(256) void k2b_mfma(const u16* adjb, const u16* wembT, u16* weff)
{
    int tid = threadIdx.x, wave = tid>>6, lane = tid&63;
    int m = lane&15, quad = lane>>4;
    const u16* ar = adjb + (wave*16 + m)*64 + quad*8;
    short8 a0 = *(const short8*)ar;
    short8 a1 = *(const short8*)(ar + 32);
    int col = blockIdx.x*16 + m;
    const u16* br = wembT + col*64 + quad*8;
    short8 b0 = *(const short8*)br;
    short8 b1 = *(const short8*)(br + 32);
    f32x4 acc = {0.f,0.f,0.f,0.f};
    acc = MFMA16(a0, b0, acc);
    acc = MFMA16(a1, b1, acc);
    #pragma unroll
    for (int r = 0; r < 4; ++r)
        weff[(size_t)(wave*16 + quad*4 + r)*1024 + blockIdx.x*16 + m] = f2bf(acc[r]);
}

// KVW: Vw = V@Weff (per node), vbias = V@beff
__global__ __launch_bounds__(256) void kvw(const u16* vslow, const u16* weff, const float* beff,
                                           u16* vw, float* vbias)
{
    __shared__ float Vs[256];
    int tid = threadIdx.x, b = blockIdx.x;
    Vs[tid] = bf2f(vslow[tid]);
    __syncthreads();
    if (b < 256){
        int idx = b*256 + tid;
        int j = idx >> 6, kf = idx & 63;
        int n = j >> 4, i = j & 15;
        float a = 0.f;
        #pragma unroll
        for (int d = 0; d < 16; ++d) a += Vs[i*16+d]*bf2f(weff[(size_t)(n*16+d)*64 + kf]);
        vw[(size_t)j*64 + kf] = f2bf(a);
    } else {
        int o = (b-256)*256 + tid;
        int n = o >> 4, i = o & 15;
        float a = 0.f;
        #pragma unroll
        for (int d = 0; d < 16; ++d) a += Vs[i*16+d]*beff[n*16+d];
        vbias[o] = a;
    }
}

// K3_stats (B-in-regs): grid 1024 = 32 colgroups x 32 rowchunks. No stores.
__global__ __launch_bounds__(256) void k3_stats(const u16* x, const u16* weff, const float* beff,
                                                const u16* vw, const float* vbias, float* s2)
{
    __shared__ float red[12];
    int tid = threadIdx.x, wave = tid>>6, lane = tid&63;
    int m = lane&15, quad = lane>>4;
    int cg = blockIdx.x & 31, rc = blockIdx.x >> 5;
    int col0 = cg*32 + m, col1 = col0 + 16;
    short8 b00 = *(const short8*)(weff + (size_t)col0*64 + quad*8);
    short8 b01 = *(const short8*)(weff + (size_t)col0*64 + quad*8 + 32);
    short8 b10 = *(const short8*)(weff + (size_t)col1*64 + quad*8);
    short8 b11 = *(const short8*)(weff + (size_t)col1*64 + quad*8 + 32);
    short8 v00 = *(const short8*)(vw + (size_t)col0*64 + quad*8);
    short8 v01 = *(const short8*)(vw + (size_t)col0*64 + quad*8 + 32);
    short8 v10 = *(const short8*)(vw + (size_t)col1*64 + quad*8);
    short8 v11 = *(const short8*)(vw + (size_t)col1*64 + quad*8 + 32);
    float be0 = beff[col0], be1 = beff[col1];
    float vb0 = vbias[col0], vb1 = vbias[col1];
    float psum=0.f, pssq=0.f, pabsv=0.f;
    const u16* xbase = x + (size_t)(rc*1024 + wave*256 + m)*64 + quad*8;
    #pragma unroll 4
    for (int it = 0; it < 16; ++it){
        const u16* xr = xbase + (size_t)it*16*64;
        short8 a0 = *(const short8*)xr;
        short8 a1 = *(const short8*)(xr + 32);
        f32x4 zc = {0.f,0.f,0.f,0.f};
        f32x4 c0 = MFMA16(a0, b00, zc);
        c0 = MFMA16(a1, b01, c0);
        f32x4 c1 = MFMA16(a0, b10, zc);
        c1 = MFMA16(a1, b11, c1);
        f32x4 w0 = MFMA16(a0, v00, zc);
        w0 = MFMA16(a1, v01, w0);
        f32x4 w1 = MFMA16(a0, v10, zc);
        w1 = MFMA16(a1, v11, w1);
        #pragma unroll
        for (int r = 0; r < 4; ++r){
            float f0 = c0[r] + be0, f1 = c1[r] + be1;
            psum += f0 + f1; pssq += f0*f0 + f1*f1;
            pabsv += fabsf(w0[r] + vb0) + fabsf(w1[r] + vb1);
        }
    }
    #pragma unroll
    for (int off = 32; off > 0; off >>= 1){
        psum  += __shfl_xor(psum, off);
        pssq  += __shfl_xor(pssq, off);
        pabsv += __shfl_xor(pabsv, off);
    }
    if (lane == 0){ red[wave*3] = psum; red[wave*3+1] = pssq; red[wave*3+2] = pabsv; }
    __syncthreads();
    if (tid == 0){
        for (int k = 0; k < 3; ++k)
            s2[blockIdx.x*3 + k] = red[k] + red[3+k] + red[6+k] + red[9+k];
    }
}

// K3b: ctrl regulator + build bex dynamic rows (16-31 Bc, 33-34 e0/e1)
__global__ __launch_bounds__(256) void k3b_ctrl(const u16* wslow,
    const u16* vslow, const u16* wfast, const u16* wq, const u16* basis,
    const u16* w1, const u16* b1, const u16* g, const u16* be, const u16* w2, const u16* b2,
    const float* s2, float* scal, u16* bex)
{
    __shared__ double sred[4];
    __shared__ float ctrl2s;
    int tid = threadIdx.x;
    double s=0, ss=0, sv=0;
    for (int i = tid; i < 1024; i += 256){
        s += (double)s2[i*3]; ss += (double)s2[i*3+1]; sv += (double)s2[i*3+2];
    }
    float wf = bf2f(wslow[tid]);
    double nq = (double)(wf*wf);
    double S  = blk_red(s,  sred, tid);
    double SS = blk_red(ss, sred, tid);
    double SV = blk_red(sv, sred, tid);
    double NQ = blk_red(nq, sred, tid);
    if (tid == 0){
        double M = 33554432.0;
        float sg[3];
        sg[0] = (float)((SS - S*S/M)/(M - 1.0));
        sg[1] = (float)(SV / M);
        sg[2] = sqrtf((float)NQ);
        float o[3];
        run_regulator(w1,b1,g,be,w2,b2, sg, 3, o);
        scal[1] = o[0]; scal[2] = o[2];
        ctrl2s = o[2];
    }
    __syncthreads();
    float ctrl2 = ctrl2s;
    if (tid < 64){
        #pragma unroll
        for (int j = 0; j < 4; ++j){
            int idx = tid*4 + j;
            int d = idx >> 4, k = idx & 15;
            bex[(16+d)*16+k] = f2bf(bf2f(vslow[idx]) + ctrl2*bf2f(wfast[idx]));
        }
    } else if (tid < 96){
        int a = (tid-64) >> 4, k = (tid-64) & 15;
        float e = 0.f;
        for (int d = 0; d < 16; ++d){
            float bq = 0.f;
            for (int j = 0; j < 16; ++j) bq += bf2f(basis[a*16+j])*bf2f(wq[j*16+d]);
            e += bq*(bf2f(vslow[d*16+k]) + ctrl2*bf2f(wfast[d*16+k]));
        }
        bex[(33+a)*16+k] = f2bf(0.25f*e);
    }
}

// KBW: build Wc[(n,d)][64], Sw[(n,j)][64], bc[1024], sb[192]
__global__ __launch_bounds__(256) void kbw(const u16* bex, const u16* weff, const float* beff,
                                           const u16* gateb, u16* wc, u16* sw,
                                           float* bc, float* sb)
{
    __shared__ float BcL[256], gvL[16], e0L[16], e1L[16];
    int tid = threadIdx.x;
    if (tid < 256) BcL[tid] = bf2f(bex[(16 + (tid>>4))*16 + (tid&15)]);
    if (tid < 16){
        gvL[tid] = bf2f(bex[32*16+tid]);
        e0L[tid] = bf2f(bex[33*16+tid]);
        e1L[tid] = bf2f(bex[34*16+tid]);
    }
    __syncthreads();
    int id = blockIdx.x*256 + tid;
    if (id < 65536){
        int col = id >> 6, k = id & 63;
        int n = col >> 4, d = col & 15;
        float a = 0.f;
        #pragma unroll
        for (int dd = 0; dd < 16; ++dd)
            a += BcL[d*16+dd]*bf2f(weff[(size_t)(n*16+dd)*64 + k]);
        wc[(size_t)col*64 + k] = f2bf(a);
    } else if (id < 77824){
        int j2 = id - 65536;
        int scol = j2 >> 6, k = j2 & 63;
        int n = scol/3, j = scol - n*3;
        const float* sr = (j==0) ? gvL : (j==1) ? e0L : e1L;
        float a = 0.f;
        #pragma unroll
        for (int dd = 0; dd < 16; ++dd)
            a += sr[dd]*bf2f(weff[(size_t)(n*16+dd)*64 + k]);
        sw[(size_t)scol*64 + k] = f2bf(a);
    } else if (id < 78848){
        int col = id - 77824;
        int n = col >> 4, d = col & 15;
        float a = 0.f;
        #pragma unroll
        for (int dd = 0; dd < 16; ++dd) a += BcL[d*16+dd]*beff[n*16+dd];
        bc[col] = a;
    } else if (id < 79040){
        int s = id - 78848;
        int n = s/3, j = s - n*3;
        const float* sr = (j==0) ? gvL : (j==1) ? e0L : e1L;
        float a = 0.f;
        #pragma unroll
        for (int dd = 0; dd < 16; ++dd) a += sr[dd]*beff[n*16+dd];
        if (j == 0) a += bf2f(gateb[0]);
        sb[s] = a;
    }
}

// K4_stats: gates/softmax/entropy + per-node stats from x. 2048 blocks x 16 rows.
#define SCP 193
__global__ __launch_bounds__(256) void k4_stats(const u16* x, const u16* wc, const u16* sw,
    const float* bc, const float* sb, const float* scal, float* wbuf, float* s3)
{
    __shared__ float sc[16*SCP];
    __shared__ float gt[1024];
    __shared__ float entp[256];
    __shared__ float snode[128];
    int tid = threadIdx.x, wave = tid>>6, lane = tid&63;
    int m = lane&15, quad = lane>>4;
    int row0 = blockIdx.x*16;
    const u16* xr = x + (row0 + m)*64 + quad*8;
    short8 a0 = *(const short8*)xr;
    short8 a1 = *(const short8*)(xr + 32);
    float ctrl0 = scal[1];
    #pragma unroll
    for (int tt = 0; tt < 3; ++tt){
        int ct = wave*3 + tt;
        int scol = ct*16 + m;
        const u16* br = sw + (size_t)scol*64 + quad*8;
        short8 b0 = *(const short8*)br;
        short8 b1 = *(const short8*)(br + 32);
        f32x4 zc = {0.f,0.f,0.f,0.f};
        f32x4 c = MFMA16(a0, b0, zc);
        c = MFMA16(a1, b1, c);
        float sbv = sb[scol];
        #pragma unroll
        for (int r = 0; r < 4; ++r)
            sc[(quad*4+r)*SCP + scol] = c[r] + sbv;
    }
    __syncthreads();
    {
        int n = tid & 63, rgrp = tid >> 6;
        float ent = 0.f;
        #pragma unroll
        for (int rr = 0; rr < 4; ++rr){
            int row = rgrp*4 + rr;
            float gd  = sc[row*SCP + 3*n];
            float e0d = sc[row*SCP + 3*n + 1];
            float e1d = sc[row*SCP + 3*n + 2];
            float gate = ctrl0 / (1.f + __expf(-gd));
            float l0 = gate*e0d, l1 = gate*e1d;
            float w1v = 1.f/(1.f + __expf(l0 - l1));
            float w0v = 1.f - w1v;
            ent += -(w0v*__logf(w0v + 1e-8f) + w1v*__logf(w1v + 1e-8f));
            gt[row*64 + n] = gate;
            float2 wv; wv.x = gate; wv.y = w0v;
            *(float2*)(wbuf + (size_t)(row0 + row)*128 + n*2) = wv;
        }
        entp[tid] = ent;
    }
    __syncthreads();
    #pragma unroll
    for (int tt = 0; tt < 16; ++tt){
        int n = wave*16 + tt;
        int col = n*16 + m;
        const u16* br = wc + (size_t)col*64 + quad*8;
        short8 b0 = *(const short8*)br;
        short8 b1 = *(const short8*)(br + 32);
        f32x4 zc = {0.f,0.f,0.f,0.f};
        f32x4 c = MFMA16(a0, b0, zc);
        c = MFMA16(a1, b1, c);
        float bcv = bc[col];
        float ps = 0.f, pq = 0.f;
        #pragma unroll
        for (int r = 0; r < 4; ++r){
            float gate = gt[(quad*4+r)*64 + n];
            float xp = gate*(c[r] + bcv);
            ps += xp; pq += xp*xp;
        }
        #pragma unroll
        for (int off = 32; off > 0; off >>= 1){
            ps += __shfl_xor(ps, off);
            pq += __shfl_xor(pq, off);
        }
        if (lane == 0){ snode[n] = ps; snode[64+n] = pq; }
    }
    __syncthreads();
    if (tid < 192){
        float v;
        if (tid < 128) v = snode[tid];
        else { int n = tid-128; v = entp[n]+entp[64+n]+entp[128+n]+entp[192+n]; }
        s3[(size_t)blockIdx.x*192 + tid] = v;
    }
}

// K5a: parallel column reduction of s3[2048][192] -> dred[192]
__global__ __launch_bounds__(256) void k5a_red(const float* s3, double* dred)
{
    __shared__ double sred[4];
    int tid = threadIdx.x, col = blockIdx.x;
    double a = 0;
    for (int i = tid; i < 2048; i += 256) a += (double)s3[(size_t)i*192 + col];
    #pragma unroll
    for (int off = 32; off > 0; off >>= 1) a += __shfl_xor(a, off);
    if ((tid & 63) == 0) sred[tid >> 6] = a;
    __syncthreads();
    if (tid == 0) dred[col] = sred[0]+sred[1]+sred[2]+sred[3];
}

// K5b: per-node regulator -> infl[64]; entropy(node63), ortho. 1 block, 64 threads.
__global__ __launch_bounds__(64) void k5b_infl(const u16* basis,
    const u16* w1, const u16* b1, const u16* g, const u16* be, const u16* w2, const u16* b2,
    const double* dred, float* scal, void* dout)
{
    int n = threadIdx.x;
    int isfp32 = scal[127] != 0.f;
    double sum = dred[n], ssq = dred[64+n], ent = dred[128+n];
    double Mn = 524288.0;
    float varn = (float)((ssq - sum*sum/Mn)/(Mn - 1.0));
    float entm = (float)(ent / 32768.0);
    float b0[16], b1v[16];
    for (int d = 0; d < 16; ++d){ b0[d] = bf2f(basis[d]); b1v[d] = bf2f(basis[16+d]); }
    float g00=0.f, g01=0.f, g11=0.f;
    for (int d = 0; d < 16; ++d){ g00 += b0[d]*b0[d]; g01 += b0[d]*b1v[d]; g11 += b1v[d]*b1v[d]; }
    float ortho = sqrtf((g00-1.f)*(g00-1.f) + 2.f*g01*g01 + (g11-1.f)*(g11-1.f));
    float sg[3] = {varn, entm, ortho};
    float o[3];
    run_regulator(w1,b1,g,be,w2,b2, sg, 3, o);
    scal[4+n] = o[0];
    if (n == 63){ scal[68] = entm;  store_out(dout, OUT_ENT,   entm,  isfp32); }
    if (n == 0) { scal[69] = ortho; store_out(dout, OUT_ORTHO, ortho, isfp32); }
}

// K6: full-K readout, gwP padded stride 65 (conflict-free), XSP=132.
#define XSP 132
__global__ __launch_bounds__(256) void k6_read(const u16* x, const float* wbuf,
    const u16* wc, const float* bc, const u16* wcat,
    const u16* basis, const u16* bread, const float* scal,
    void* dout, float* hbuf, float* s4)
{
    __shared__ unsigned gwP[64*65];              // [64 rows][65] lo=gate, hi=w0 (bf16), padded
    __shared__ u16 xs[4*16*XSP];
    __shared__ float infl_s[64], b0s[16], b1s[16], brd[16];
    __shared__ float red[8];
    int tid = threadIdx.x;
    int isfp32 = scal[127] != 0.f;
    for (int i = tid; i < 4096; i += 256){
        float2 gw = *(const float2*)(wbuf + (size_t)blockIdx.x*8192 + i*2);
        gwP[(i >> 6)*65 + (i & 63)] = ((unsigned)f2bf(gw.y) << 16) | (unsigned)f2bf(gw.x);
    }
    if (tid < 64) infl_s[tid] = scal[4+tid];
    if (tid < 16){
        b0s[tid] = bf2f(basis[tid]);
        b1s[tid] = bf2f(basis[16+tid]);
        brd[tid] = (tid < 10) ? bf2f(bread[tid]) : 0.f;
    }
    __syncthreads();
    int wave = tid>>6, lane = tid&63;
    int m = lane&15, quad = lane>>4;
    int row = blockIdx.x*64 + wave*16 + m;
    const u16* xr = x + (size_t)row*64 + quad*8;
    short8 a0 = *(const short8*)xr;
    short8 a1 = *(const short8*)(xr + 32);
    u16* xsw = xs + wave*16*XSP;
    f32x4 acc0 = {0.f,0.f,0.f,0.f}, acc1 = {0.f,0.f,0.f,0.f};
    float psum = 0.f, pssq = 0.f;
    for (int c8 = 0; c8 < 8; ++c8){
        #pragma unroll
        for (int t = 0; t < 8; ++t){
            int n = c8*8 + t;
            int col = n*16 + m;
            const u16* br = wc + (size_t)col*64 + quad*8;
            short8 b0 = *(const short8*)br;
            short8 b1 = *(const short8*)(br + 32);
            f32x4 zc = {0.f,0.f,0.f,0.f};
            f32x4 c = MFMA16(a0, b0, zc);
            c = MFMA16(a1, b1, c);
            float bcv = bc[col];
            float fi = infl_s[n], om = 1.f - fi;
            #pragma unroll
            for (int r = 0; r < 4; ++r){
                unsigned gv = gwP[(wave*16 + quad*4 + r)*65 + n];
                float gate = bf2f((u16)(gv & 0xFFFFu));
                float w0v  = bf2f((u16)(gv >> 16));
                float xp = gate*(c[r] + bcv);
                float xf = om*xp + fi*(w0v*b0s[m] + (1.f-w0v)*b1s[m]);
                psum += xf; pssq += xf*xf;
                xsw[(quad*4+r)*XSP + t*16 + m] = f2bf(xf);
            }
        }
        #pragma unroll
        for (int kk = 0; kk < 4; ++kk){
            short8 af = *(const short8*)(xsw + m*XSP + kk*32 + quad*8);
            short8 bb0 = *(const short8*)(wcat + m*1024      + c8*128 + kk*32 + quad*8);
            short8 bb1 = *(const short8*)(wcat + (16+m)*1024 + c8*128 + kk*32 + quad*8);
            acc0 = MFMA16(af, bb0, acc0);
            acc1 = MFMA16(af, bb1, acc1);
        }
    }
    int rowbase = blockIdx.x*64 + wave*16 + quad*4;
    #pragma unroll
    for (int r = 0; r < 4; ++r){
        int rowg = rowbase + r;
        if (m < 10) store_out(dout, rowg*10 + m, acc0[r] + brd[m], isfp32);
        else        hbuf[rowg*8 + (m-10)] = fmaxf(acc0[r], 0.f);
        if (m < 2)  hbuf[rowg*8 + 6 + m]  = fmaxf(acc1[r], 0.f);
    }
    #pragma unroll
    for (int off = 32; off > 0; off >>= 1){
        psum += __shfl_xor(psum, off);
        pssq += __shfl_xor(pssq, off);
    }
    if (lane == 0){ red[wave] = psum; red[4+wave] = pssq; }
    __syncthreads();
    if (tid == 0){
        s4[blockIdx.x*2]   = red[0]+red[1]+red[2]+red[3];
        s4[blockIdx.x*2+1] = red[4]+red[5]+red[6]+red[7];
    }
}

// K7: gain regulator (s4 512 rows x 2)
__global__ __launch_bounds__(256) void k7_gain(
    const u16* w1, const u16* b1, const u16* g, const u16* be, const u16* w2, const u16* b2,
    const float* s4, float* scal)
{
    __shared__ double sred[4];
    int tid = threadIdx.x;
    double s=0, ss=0;
    for (int i = tid; i < 512; i += 256){ s += (double)s4[i*2]; ss += (double)s4[i*2+1]; }
    double S  = blk_red(s,  sred, tid);
    double SS = blk_red(ss, sred, tid);
    if (tid == 0){
        double M = 33554432.0;
        float sg[2];
        sg[0] = (float)((SS - S*S/M)/(M - 1.0));
        sg[1] = scal[68];
        float o[3];
        run_regulator(w1,b1,g,be,w2,b2, sg, 2, o);
        scal[3] = o[0];
    }
}

// K8: proj = (h @ sc_w2^T) * gain
__global__ __launch_bounds__(256) void k8_proj(const float* hbuf, const u16* scw2,
                                               const float* scal, void* dout)
{
    __shared__ float w2s[32];
    int tid = threadIdx.x;
    int isfp32 = scal[127] != 0.f;
    if (tid < 32) w2s[tid] = bf2f(scw2[tid]);
    __syncthreads();
    int b = blockIdx.x*256 + tid;
    float gain = scal[3];
    const float* h = hbuf + (size_t)b*8;
    float hv[8];
    #pragma unroll
    for (int k = 0; k < 8; ++k) hv[k] = h[k];
    #pragma unroll
    for (int i = 0; i < 4; ++i){
        float o = 0.f;
        #pragma unroll
        for (int k = 0; k < 8; ++k) o += hv[k]*w2s[i*8+k];
        store_out(dout, OUT_PROJ + b*4 + i, o*gain, isfp32);
    }
}

extern "C" void kernel_launch(void* const* d_in, const int* in_sizes, int n_in,
                              void* d_out, int out_size, void* d_ws, size_t ws_size,
                              hipStream_t stream)
{
    if (ws_size < WS_NEEDED) return;

    char* ws = (char*)d_ws;
    float* scal  = (float*)(ws + OFF_SCAL);
    u16*   adjb  = (u16*)  (ws + OFF_ADJ);
    float* beff  = (float*)(ws + OFF_BEFF);
    u16*   weff  = (u16*)  (ws + OFF_WEFF);
    u16*   wcat  = (u16*)  (ws + OFF_WCAT);
    float* s1    = (float*)(ws + OFF_S1);
    float* s2    = (float*)(ws + OFF_S2);
    float* s3    = (float*)(ws + OFF_S3);
    float* s4    = (float*)(ws + OFF_S4);
    float* hbuf  = (float*)(ws + OFF_H);
    float* wbuf  = (float*)(ws + OFF_W01);
    u16*   can   = (u16*)  (ws + OFF_CAN);
    u16*   bex   = (u16*)  (ws + OFF_BEX);
    u16*   wembT = (u16*)  (ws + OFF_WET);
    u16*   vw    = (u16*)  (ws + OFF_VW);
    float* vbias = (float*)(ws + OFF_VB);
    u16*   wc    = (u16*)  (ws + OFF_WC);
    u16*   sw    = (u16*)  (ws + OFF_SW);
    float* bc    = (float*)(ws + OFF_BC2);
    float* sb    = (float*)(ws + OFF_SB);
    double* dred = (double*)(ws + OFF_DR);

    static const int sidx[36] = {2,3,4,5,6,7,8,9,10,11,13,15,
        16,17,18,19,20,21, 22,23,24,25,26,27, 28,29,30,31,32,33, 34,35,36,37,38,39};
    static const int scnt[36] = {1024,4096,4096,256,256,16,1,256,32,256,32,10,
        48,16,16,16,48,3, 48,16,16,16,48,3, 48,16,16,16,48,3, 32,16,16,16,48,3};
    SmallTab t;
    const u16* canp[40];
    {
        int off = (int)CAN_SMALL;
        for (int j = 0; j < 36; ++j){
            t.src[j] = d_in[sidx[j]];
            t.cnt[j] = scnt[j];
            t.off[j] = off;
            canp[sidx[j]] = can + off;
            off += (scnt[j] + 7) & ~7;
        }
    }
    canp[0]  = can + CAN_X;
    canp[1]  = can + CAN_WEMB;
    canp[12] = can + CAN_SCW1;
    canp[14] = can + CAN_WREAD;

    const u16* pr_[6]; const u16* cr_[6]; const u16* sr_[6]; const u16* sc_[6];
    for (int i = 0; i < 6; ++i){
        pr_[i] = canp[16+i]; cr_[i] = canp[22+i];
        sr_[i] = canp[28+i]; sc_[i] = canp[34+i];
    }

    kp_probe<<<1,   256, 0, stream>>>((const u16*)d_in[0], scal);
    kc_big  <<<1024,256, 0, stream>>>(d_in[0], d_in[1], d_in[14], d_in[12], can, scal);
    kc_small<<<16,  256, 0, stream>>>(t, can, scal);
    k0_wcat <<<385, 256, 0, stream>>>(canp[14], canp[12], canp[1], canp[5], canp[7],
                 wcat, wembT, bex);
    k1_embed<<<1024,256, 0, stream>>>(canp[0], canp[1], canp[2], s1);
    k2_adj  <<<1,   256, 0, stream>>>(canp[3], canp[4], canp[2],
                 pr_[0],pr_[1],pr_[2],pr_[3],pr_[4],pr_[5], s1, scal, adjb, beff);
    k2b_mfma<<<64,  256, 0, stream>>>(adjb, wembT, weff);
    kvw     <<<260, 256, 0, stream>>>(canp[5], weff, beff, vw, vbias);
    k3_stats<<<1024,256, 0, stream>>>(canp[0], weff, beff, vw, vbias, s2);
    k3b_ctrl<<<1,   256, 0, stream>>>(canp[6], canp[5], canp[9], canp[11], canp[10],
                 cr_[0],cr_[1],cr_[2],cr_[3],cr_[4],cr_[5], s2, scal, bex);
    kbw     <<<312, 256, 0, stream>>>(bex, weff, beff, canp[8], wc, sw, bc, sb);
    k4_stats<<<2048,256, 0, stream>>>(canp[0], wc, sw, bc, sb, scal, wbuf, s3);
    k5a_red <<<192, 256, 0, stream>>>(s3, dred);
    k5b_infl<<<1,   64,  0, stream>>>(canp[10],
                 sr_[0],sr_[1],sr_[2],sr_[3],sr_[4],sr_[5], dred, scal, d_out);
    k6_read <<<512, 256, 0, stream>>>(canp[0], wbuf, wc, bc, wcat, canp[10], canp[15],
                 scal, d_out, hbuf, s4);
    k7_gain <<<1,   256, 0, stream>>>(
                 sc_[0],sc_[1],sc_[2],sc_[3],sc_[4],sc_[5], s4, scal);
    k8_proj <<<128, 256, 0, stream>>>(hbuf, canp[13], scal, d_out);
}